// Round 3
// baseline (64.937 us; speedup 1.0000x reference)
//
#include <hip/hip_runtime.h>
#include <math.h>

#define QN 8
#define NDIMS 2
#define LATENT 64
#define OUTC 32     // Q + Q + Q*NDIMS
#define IT 16       // i-rows per thread in pair kernel

// ---------------------------------------------------------------------------
// Phase 1: per-point feature MLP + derived quantities.
// ONE POINT PER THREAD, all in registers. No LDS, no syncs, no libm.
// 64-thread blocks -> 64 blocks -> one block per CU, 1 wave each; per-thread
// critical path ~2.5K VALU ops. W1/b1/W2/b2 are thread-invariant -> compiler
// emits s_load + scalar-operand v_fma (1 SGPR src per VALU op is legal).
// Store per point (32 floats):
//   [0:8)   u[q]   = w*sqrt(s)*2^0.25     (so uA*uB = wA*wB*sqrt(2 sA sB))
//   [8:16)  ssq[q] = s*s
//   [16:24) cos(2*pi*phi[q])
//   [24:32) sin(2*pi*phi[q])
// ---------------------------------------------------------------------------
__global__ __launch_bounds__(64) void feat_kernel(
    const float* __restrict__ x, const float* __restrict__ y, int n,
    const float* __restrict__ W1, const float* __restrict__ b1,
    const float* __restrict__ W2, const float* __restrict__ b2,
    float* __restrict__ featX, float* __restrict__ featY)
{
    const int gp   = blockIdx.x * 64 + threadIdx.x;
    const int npts = 2 * n;
    if (gp >= npts) return;

    const float* p = (gp < n) ? (x + 2 * gp) : (y + 2 * (gp - n));
    float p0 = p[0], p1 = p[1];

    const float kScale = 1.0507009873554804934193349852946f;
    const float kAlpha = 1.6732632423543772848170429916717f;

    // h = selu(W1 p + b1)  — 64 regs, fully unrolled (static indices only)
    float h[LATENT];
    #pragma unroll
    for (int k = 0; k < LATENT; ++k) {
        float z = fmaf(W1[2 * k], p0, fmaf(W1[2 * k + 1], p1, b1[k]));
        h[k] = kScale * (z > 0.f ? z : kAlpha * (__expf(z) - 1.f));
    }

    // a = softplus(W2 h + b2) — W2 offsets compile-time constant -> s_load
    float a[OUTC];
    #pragma unroll
    for (int o = 0; o < OUTC; ++o) {
        const float* w = W2 + o * LATENT;
        float z0 = b2[o], z1 = 0.f, z2 = 0.f, z3 = 0.f;
        #pragma unroll
        for (int k = 0; k < LATENT; k += 4) {
            z0 = fmaf(w[k + 0], h[k + 0], z0);
            z1 = fmaf(w[k + 1], h[k + 1], z1);
            z2 = fmaf(w[k + 2], h[k + 2], z2);
            z3 = fmaf(w[k + 3], h[k + 3], z3);
        }
        float z = (z0 + z1) + (z2 + z3);
        // stable softplus: max(z,0) + log(1 + exp(-|z|)), fast intrinsics
        a[o] = fmaxf(z, 0.f) + __logf(1.f + __expf(-fabsf(z)));
    }

    // derived per-q features, vectorized stores (4x float4 per point)
    float4 uo, so, co, sno;
    float* uop = &uo.x; float* sop = &so.x; float* cop = &co.x; float* snp = &sno.x;
    float* fo = (gp < n) ? (featX + 32 * gp) : (featY + 32 * (gp - n));
    const float TWO_PI  = 6.283185307179586f;
    const float ROOT4_2 = 1.18920711500272107f;   // 2^(1/4)
    #pragma unroll
    for (int qq = 0; qq < 2; ++qq) {
        #pragma unroll
        for (int r = 0; r < 4; ++r) {
            int q = 4 * qq + r;
            float w  = a[q];
            float s  = a[QN + q];
            float f0 = a[2 * QN + 2 * q];
            float f1 = a[2 * QN + 2 * q + 1];
            float phi = fmaf(f0, p0, f1 * p1);
            float rr  = phi - floorf(phi);        // reduce to [0,1) revolutions
            float ang = TWO_PI * rr;
            uop[r] = w * sqrtf(s) * ROOT4_2;
            sop[r] = s * s;
            cop[r] = __cosf(ang);
            snp[r] = __sinf(ang);
        }
        *(float4*)(fo + 4 * qq)          = uo;
        *(float4*)(fo + QN + 4 * qq)     = so;
        *(float4*)(fo + 2 * QN + 4 * qq) = co;
        *(float4*)(fo + 3 * QN + 4 * qq) = sno;
    }
}

// ---------------------------------------------------------------------------
// Phase 2: pairwise kernel — UNCHANGED from round 2 (clean differential;
// inferred ~2.9 us, near the 16.7MB/6.3TBps = 2.7 us write floor).
// out[i,j] = sum_q uA*uB/s2 * exp(-d2/s2) * (cA*cB + snA*snB),  s2 = ssqA+ssqB
// ---------------------------------------------------------------------------
__global__ __launch_bounds__(256) void pair_kernel(
    const float* __restrict__ x, const float* __restrict__ y, int n,
    const float* __restrict__ fA, const float* __restrict__ fB,
    float* __restrict__ out)
{
    int j = blockIdx.x * 256 + threadIdx.x;
    if (j >= n) return;
    int i0 = blockIdx.y * IT;

    float uB[QN], ssB[QN], cB[QN], snB[QN];
    const float* fb = fB + 32 * j;
    #pragma unroll
    for (int q = 0; q < QN; ++q) {
        uB[q]  = fb[q];
        ssB[q] = fb[QN + q];
        cB[q]  = fb[2 * QN + q];
        snB[q] = fb[3 * QN + q];
    }
    float y0 = y[2 * j], y1 = y[2 * j + 1];

    #pragma unroll 4
    for (int ii = 0; ii < IT; ++ii) {
        int i = i0 + ii;
        if (i >= n) break;
        const float* fa = fA + 32 * i;           // wave-uniform -> s_load
        float dx = x[2 * i]     - y0;
        float dy = x[2 * i + 1] - y1;
        float d2 = fmaf(dx, dx, dy * dy);
        float acc = 0.f;
        #pragma unroll
        for (int q = 0; q < QN; ++q) {
            float s2  = fa[QN + q] + ssB[q];
            float inv = __builtin_amdgcn_rcpf(s2);
            float e   = __expf(-d2 * inv);
            float g   = fa[q] * uB[q] * inv * e;
            float c   = fmaf(fa[2 * QN + q], cB[q], fa[3 * QN + q] * snB[q]);
            acc = fmaf(g, c, acc);
        }
        out[(long)i * n + j] = acc;
    }
}

extern "C" void kernel_launch(void* const* d_in, const int* in_sizes, int n_in,
                              void* d_out, int out_size, void* d_ws, size_t ws_size,
                              hipStream_t stream)
{
    const float* x  = (const float*)d_in[0];
    const float* y  = (const float*)d_in[1];
    const float* W1 = (const float*)d_in[2];
    const float* b1 = (const float*)d_in[3];
    const float* W2 = (const float*)d_in[4];
    const float* b2 = (const float*)d_in[5];
    float* out = (float*)d_out;

    int n = in_sizes[0] / NDIMS;     // 2048

    float* featX = (float*)d_ws;
    float* featY = featX + (size_t)n * 32;

    int npts = 2 * n;
    hipLaunchKernelGGL(feat_kernel, dim3((npts + 63) / 64), dim3(64), 0, stream,
                       x, y, n, W1, b1, W2, b2, featX, featY);

    dim3 grid((n + 255) / 256, (n + IT - 1) / IT);
    hipLaunchKernelGGL(pair_kernel, grid, dim3(256), 0, stream,
                       x, y, n, featX, featY, out);
}